// Round 7
// baseline (3378.293 us; speedup 1.0000x reference)
//
#include <hip/hip_runtime.h>
#include <hip/hip_bf16.h>
#include <stdint.h>

#define T_STEPS 1024
#define NH1 1024
#define NH2 512
#define D_IN 300
#define W1_LD 1324
#define W2_LD 1536
#define NVG 50000
#define NVS 25000

typedef unsigned long long u64;
typedef __bf16 bf16x8 __attribute__((ext_vector_type(8)));
typedef short s16x8 __attribute__((ext_vector_type(8)));
typedef float f32x4 __attribute__((ext_vector_type(4)));

// ---------------------------------------------------------------------------
// Kernel 1: E[t][r] = b1[r] + sum_c W1[r][c] * X[idx[t]][c]   (c < 300)
// Also zeroes the 64B election control block (lives in the tail of `out`,
// which gemm/norm overwrite long after the election is done).
// ---------------------------------------------------------------------------
__global__ __launch_bounds__(256) void e_kernel(
    const float* __restrict__ X,
    const float* __restrict__ W1,
    const float* __restrict__ b1,
    const int* __restrict__ idx,
    float* __restrict__ E,
    unsigned* __restrict__ ctl)
{
  if (blockIdx.x == 0 && threadIdx.x < 16) ctl[threadIdx.x] = 0u;

  __shared__ float Xs[32 * 300];
  const int rb = blockIdx.x & 7;
  const int tb = blockIdx.x >> 3;
  const int r0 = rb * 128;
  const int t0 = tb * 32;

  for (int t = 0; t < 32; ++t) {
    int node = idx[t0 + t];
    for (int c = threadIdx.x; c < 300; c += 256)
      Xs[t * 300 + c] = X[(size_t)node * D_IN + c];
  }
  __syncthreads();

  const int rl = threadIdx.x & 127;
  const int th = threadIdx.x >> 7;
  const int tbase = th * 16;
  const int r = r0 + rl;

  float acc[16];
  const float bias = b1[r];
#pragma unroll
  for (int tt = 0; tt < 16; ++tt) acc[tt] = bias;

  const float* wrow = W1 + (size_t)r * W1_LD;
  for (int c0 = 0; c0 < 300; c0 += 4) {
    float w0 = wrow[c0 + 0];
    float w1 = wrow[c0 + 1];
    float w2 = wrow[c0 + 2];
    float w3 = wrow[c0 + 3];
#pragma unroll
    for (int tt = 0; tt < 16; ++tt) {
      const float* xr = Xs + (tbase + tt) * 300 + c0;
      acc[tt] += w0 * xr[0] + w1 * xr[1] + w2 * xr[2] + w3 * xr[3];
    }
  }
#pragma unroll
  for (int tt = 0; tt < 16; ++tt)
    E[(size_t)(t0 + tbase + tt) * NH1 + r] = acc[tt];
}

// ---------------------------------------------------------------------------
// Kernel 2: persistent RNN — SINGLE-XCD team, dirty-L2 handoff.
//
// Election (proven r2-r6): 512 co-resident blocks rank themselves per
// physical XCD (HW_REG_XCC_ID); first XCD to fill 64 slots wins; its ranks
// 0..63 run the RNN, everyone else exits.
//
// Cache model derived from r2-r6 measurements:
//   * store `sc0`      -> lands DIRTY in shared XCD L2, never HBM (r3/r4).
//   * load  `sc0 sc1`  -> memory-side WITH coherence probe: correct,
//                         ~700-800cy (r4 champion, 2176us).
//   * load  `sc0` only -> memory-side WITHOUT probe: ~790cy AND stale
//                         (r2/r3 cadence-proportional spin cost) — L1 was
//                         never consulted, which is why r5's buffer_inv+sc0
//                         failed.
//   * UNTESTED fast path this round: buffer_inv (invalidate vL1) + PLAIN
//     load -> L1 miss -> shared-L2 dirty hit (~250cy). If buffer_inv is
//     inert, plain loads hit stale L1 at ~100cy (cheap), and the coherent
//     round every 3rd spin (round 0 first) guarantees progress at ~r4 cost.
// Tag-in-8B-atom + quad-buffer protocol unchanged.
// ---------------------------------------------------------------------------
#define POLL6(SUFFIX)                                                        \
  asm volatile(                                                              \
      "global_load_dwordx2 %0, %6, off " SUFFIX "\n\t"                       \
      "global_load_dwordx2 %1, %6, off offset:512 " SUFFIX "\n\t"            \
      "global_load_dwordx2 %2, %6, off offset:1024 " SUFFIX "\n\t"           \
      "global_load_dwordx2 %3, %6, off offset:1536 " SUFFIX "\n\t"           \
      "global_load_dwordx2 %4, %7, off " SUFFIX "\n\t"                       \
      "global_load_dwordx2 %5, %7, off offset:512 " SUFFIX "\n\t"            \
      "s_waitcnt vmcnt(0)"                                                   \
      : "=&v"(t1[0]), "=&v"(t1[1]), "=&v"(t1[2]), "=&v"(t1[3]),              \
        "=&v"(t2[0]), "=&v"(t2[1])                                           \
      : "v"(p1), "v"(p2)                                                     \
      : "memory")

__global__ __launch_bounds__(256, 2) void rnn_kernel(
    const float* __restrict__ W1,
    const float* __restrict__ W2,
    const float* __restrict__ b2,
    const float* __restrict__ E,
    u64* __restrict__ buf1,     // [4][1024]
    u64* __restrict__ buf2,     // [4][512]
    __hip_bfloat16* __restrict__ h2s,   // [T][512]
    unsigned* __restrict__ ctl)         // [8] cnt per XCD, [8]=winner
{
  __shared__ float lds1[2][NH1];
  __shared__ float lds2[2][NH2];
  __shared__ int s_role;

  // ---- election: find 64 co-XCD blocks ----
  if (threadIdx.x == 0) {
    int xcd;
    asm volatile("s_getreg_b32 %0, hwreg(HW_REG_XCC_ID)" : "=s"(xcd));
    xcd &= 7;
    unsigned rk = atomicAdd(&ctl[xcd], 1u);
    int role = -1;
    if (rk < 64u) {
      if (rk == 63u) atomicCAS(&ctl[8], 0u, (unsigned)(xcd + 1));
      unsigned wnr;
      while ((wnr = __hip_atomic_load(&ctl[8], __ATOMIC_RELAXED,
                                      __HIP_MEMORY_SCOPE_AGENT)) == 0u)
        __builtin_amdgcn_s_sleep(16);
      if (wnr == (unsigned)(xcd + 1)) role = (int)rk;
    }
    s_role = role;
  }
  __syncthreads();
  if (s_role < 0) return;
  const int b = s_role;                           // 0..63, all on one XCD

  const int lane = threadIdx.x & 63;
  const int w = threadIdx.x >> 6;                 // wave in block, 0..3
  const int wvid = b * 4 + w;                     // 0..255
  const int r1 = wvid * 4;
  const int r2 = wvid * 2;
  const int q = (w + b) & 3;                      // polled quarter (staggered)

  float w1r[4][16];
#pragma unroll
  for (int i = 0; i < 4; ++i)
#pragma unroll
    for (int j = 0; j < 16; ++j)
      w1r[i][j] = W1[(size_t)(r1 + i) * W1_LD + D_IN + lane + 64 * j];

  float w2r[2][24];
#pragma unroll
  for (int i = 0; i < 2; ++i)
#pragma unroll
    for (int j = 0; j < 24; ++j)
      w2r[i][j] = W2[(size_t)(r2 + i) * W2_LD + lane + 64 * j];

  const float b2a = b2[r2];
  const float b2b = b2[r2 + 1];

  for (int s = 0; s <= T_STEPS; ++s) {
    // Prefetch E for this step's h1 rows (latency overlaps the spin).
    float ev = 0.f;
    if (s < T_STEPS) ev = E[(size_t)s * NH1 + r1 + (lane & 3)];

    // ---- poll my quarter of h1(s) and h2(s-1) ----
    float v1[4] = {0.f, 0.f, 0.f, 0.f};
    float v2[2] = {0.f, 0.f};
    unsigned miss = 0;
    if (s >= 1) miss |= 0xFu;
    if (s >= 2) miss |= 0x30u;
    const u64* p1 = buf1 + (size_t)(s & 3) * NH1 + 256 * q + lane;
    const u64* p2 = buf2 + (size_t)((s - 1) & 3) * NH2 + 128 * q + lane;
    const unsigned tag1 = (unsigned)s;
    const unsigned tag2 = (unsigned)(s - 1);

    unsigned spin = 0;
    while (miss) {
      u64 t1[4], t2[2];
      if ((spin % 3u) == 0u) {
        POLL6("sc0 sc1");       // coherent tier (r4-proven), round 0 first
      } else {
        // fast tier: invalidate vL1, then PLAIN loads -> shared-L2 lookup
        asm volatile("buffer_inv\n\t"
                     "s_waitcnt vmcnt(0)" ::: "memory");
        POLL6("");
      }
      ++spin;
#pragma unroll
      for (int j = 0; j < 4; ++j)
        if ((miss & (1u << j)) && (unsigned)(t1[j] >> 32) == tag1) {
          v1[j] = __uint_as_float((unsigned)t1[j]);
          miss &= ~(1u << j);
        }
#pragma unroll
      for (int j = 0; j < 2; ++j)
        if ((miss & (0x10u << j)) && (unsigned)(t2[j] >> 32) == tag2) {
          v2[j] = __uint_as_float((unsigned)t2[j]);
          miss &= ~(0x10u << j);
        }
    }

    // ---- publish quarter to LDS, barrier ----
    const int pb = s & 1;
#pragma unroll
    for (int j = 0; j < 4; ++j) lds1[pb][256 * q + 64 * j + lane] = v1[j];
#pragma unroll
    for (int j = 0; j < 2; ++j) lds2[pb][128 * q + 64 * j + lane] = v2[j];
    __syncthreads();

    // ---- compute from LDS ----
    float a0 = 0.f, a1 = 0.f, a2 = 0.f, a3 = 0.f, a4 = 0.f, a5 = 0.f;
#pragma unroll
    for (int j = 0; j < 16; ++j) {
      float h = lds1[pb][lane + 64 * j];
      a0 += w1r[0][j] * h;
      a1 += w1r[1][j] * h;
      a2 += w1r[2][j] * h;
      a3 += w1r[3][j] * h;
      a4 += w2r[0][j] * h;
      a5 += w2r[1][j] * h;
    }
#pragma unroll
    for (int j = 0; j < 8; ++j) {
      float h = lds2[pb][lane + 64 * j];
      a4 += w2r[0][16 + j] * h;
      a5 += w2r[1][16 + j] * h;
    }

    // h1 critical path first: reduce a0..a3, store into shared L2 (sc0).
#pragma unroll
    for (int off = 32; off; off >>= 1) {
      a0 += __shfl_xor(a0, off);
      a1 += __shfl_xor(a1, off);
      a2 += __shfl_xor(a2, off);
      a3 += __shfl_xor(a3, off);
    }
    if (s < T_STEPS && lane < 4) {
      float x = (lane == 0 ? a0 : lane == 1 ? a1 : lane == 2 ? a2 : a3) + ev;
      float h = x > 0.f ? x : 0.01f * x;
      u64 pk = ((u64)(unsigned)(s + 1) << 32) | (u64)__float_as_uint(h);
      u64* dst = buf1 + (size_t)((s + 1) & 3) * NH1 + r1 + lane;
      asm volatile("global_store_dwordx2 %0, %1, off sc0"
                   :: "v"(dst), "v"(pk) : "memory");
    }

    // h2 off the critical path.
    if (s >= 1) {
#pragma unroll
      for (int off = 32; off; off >>= 1) {
        a4 += __shfl_xor(a4, off);
        a5 += __shfl_xor(a5, off);
      }
      if (lane >= 4 && lane < 6) {
        int i = lane - 4;
        float x = (i == 0 ? a4 : a5) + (i == 0 ? b2a : b2b);
        float h = x > 0.f ? x : 0.01f * x;
        u64 pk = ((u64)(unsigned)s << 32) | (u64)__float_as_uint(h);
        u64* dst = buf2 + (size_t)(s & 3) * NH2 + r2 + i;
        asm volatile("global_store_dwordx2 %0, %1, off sc0"
                     :: "v"(dst), "v"(pk) : "memory");
        h2s[(size_t)(s - 1) * NH2 + r2 + i] = __float2bfloat16(h);
      }
    }
  }
}

// ---------------------------------------------------------------------------
// Kernel 3: C[m][n] = sum_k A[m][k]*B[n][k] + bias[n]  (fp32 logits out).
// A = h2s [1024][512] bf16. B fp32 -> bf16 while staging. 256x128x64 tiles.
// ---------------------------------------------------------------------------
__global__ __launch_bounds__(256, 1) void gemm_kernel(
    const __hip_bfloat16* __restrict__ A,
    const float* __restrict__ B,
    const float* __restrict__ bias,
    float* __restrict__ C,
    int N)
{
  __shared__ short As[256 * 64];
  __shared__ short Bs[128 * 64];
  const int tid = threadIdx.x;
  const int lane = tid & 63;
  const int wv = tid >> 6;
  const int wm = (wv & 1) * 128;
  const int wn = (wv >> 1) * 64;
  const int m0 = blockIdx.x * 256;
  const int n0 = blockIdx.y * 128;
  const int ml = lane & 15;
  const int kq = lane >> 4;

  f32x4 acc[8][4];
#pragma unroll
  for (int i = 0; i < 8; ++i)
#pragma unroll
    for (int j = 0; j < 4; ++j)
      acc[i][j] = (f32x4){0.f, 0.f, 0.f, 0.f};

  for (int kb = 0; kb < 512; kb += 64) {
    __syncthreads();
#pragma unroll
    for (int q = 0; q < 8; ++q) {
      int ch = q * 256 + tid;
      int row = ch >> 3;
      int kc = ch & 7;
      int phys = kc ^ (row & 7);
      s16x8 av = *(const s16x8*)((const short*)A + (size_t)(m0 + row) * 512 + kb + kc * 8);
      *(s16x8*)(As + row * 64 + phys * 8) = av;
    }
#pragma unroll
    for (int q = 0; q < 4; ++q) {
      int ch = q * 256 + tid;
      int row = ch >> 3;
      int kc = ch & 7;
      int phys = kc ^ (row & 7);
      int gr = n0 + row;
      if (gr >= N) gr = N - 1;
      const float* src = B + (size_t)gr * 512 + kb + kc * 8;
      f32x4 f0 = *(const f32x4*)(src);
      f32x4 f1 = *(const f32x4*)(src + 4);
      bf16x8 bv;
      bv[0] = (__bf16)f0[0]; bv[1] = (__bf16)f0[1];
      bv[2] = (__bf16)f0[2]; bv[3] = (__bf16)f0[3];
      bv[4] = (__bf16)f1[0]; bv[5] = (__bf16)f1[1];
      bv[6] = (__bf16)f1[2]; bv[7] = (__bf16)f1[3];
      *(bf16x8*)(Bs + row * 64 + phys * 8) = bv;
    }
    __syncthreads();
#pragma unroll
    for (int ks = 0; ks < 2; ++ks) {
      bf16x8 af[8], bfr[4];
#pragma unroll
      for (int i = 0; i < 8; ++i) {
        int row = wm + 16 * i + ml;
        int phys = (ks * 4 + kq) ^ (row & 7);
        af[i] = *(const bf16x8*)(As + row * 64 + phys * 8);
      }
#pragma unroll
      for (int j = 0; j < 4; ++j) {
        int row = wn + 16 * j + ml;
        int phys = (ks * 4 + kq) ^ (row & 7);
        bfr[j] = *(const bf16x8*)(Bs + row * 64 + phys * 8);
      }
#pragma unroll
      for (int i = 0; i < 8; ++i)
#pragma unroll
        for (int j = 0; j < 4; ++j)
          acc[i][j] = __builtin_amdgcn_mfma_f32_16x16x32_bf16(af[i], bfr[j], acc[i][j], 0, 0, 0);
    }
  }

  float bv[4];
#pragma unroll
  for (int j = 0; j < 4; ++j) {
    int n = n0 + wn + 16 * j + ml;
    bv[j] = (n < N) ? bias[n] : 0.f;
  }
#pragma unroll
  for (int i = 0; i < 8; ++i) {
    int mrow = m0 + wm + 16 * i + kq * 4;
#pragma unroll
    for (int j = 0; j < 4; ++j) {
      int n = n0 + wn + 16 * j + ml;
      if (n < N) {
#pragma unroll
        for (int r = 0; r < 4; ++r)
          C[(size_t)(mrow + r) * N + n] = acc[i][j][r] + bv[j];
      }
    }
  }
}

// ---------------------------------------------------------------------------
// Kernel 4: in-place fp32 log-softmax per (row, segment). 2048 blocks x 256.
// ---------------------------------------------------------------------------
__global__ __launch_bounds__(256) void norm_kernel(float* __restrict__ out)
{
  const int b = blockIdx.x;
  const int t = b & 1023;
  const int seg = b >> 10;
  const size_t base = seg == 0 ? (size_t)t * NVG
                               : (size_t)1024 * NVG + (size_t)t * NVS;
  const int len = seg == 0 ? NVG : NVS;
  float* p = out + base;
  const int lane = threadIdx.x & 63;
  const int wv = threadIdx.x >> 6;
  __shared__ float red[4];

  float m = -3.0e38f;
  for (int i = threadIdx.x; i < len; i += 256)
    m = fmaxf(m, p[i]);
#pragma unroll
  for (int off = 32; off; off >>= 1) m = fmaxf(m, __shfl_xor(m, off));
  if (lane == 0) red[wv] = m;
  __syncthreads();
  m = fmaxf(fmaxf(red[0], red[1]), fmaxf(red[2], red[3]));
  __syncthreads();

  float sum = 0.f;
  for (int i = threadIdx.x; i < len; i += 256)
    sum += expf(p[i] - m);
#pragma unroll
  for (int off = 32; off; off >>= 1) sum += __shfl_xor(sum, off);
  if (lane == 0) red[wv] = sum;
  __syncthreads();
  sum = red[0] + red[1] + red[2] + red[3];
  const float lse = m + logf(sum);

  for (int i = threadIdx.x; i < len; i += 256)
    p[i] = p[i] - lse;
}

// ---------------------------------------------------------------------------
extern "C" void kernel_launch(void* const* d_in, const int* in_sizes, int n_in,
                              void* d_out, int out_size, void* d_ws, size_t ws_size,
                              hipStream_t stream) {
  const float* X  = (const float*)d_in[0];
  const float* W1 = (const float*)d_in[1];
  const float* b1 = (const float*)d_in[2];
  const float* W2 = (const float*)d_in[3];
  const float* b2 = (const float*)d_in[4];
  const float* Wg = (const float*)d_in[5];
  const float* bg = (const float*)d_in[6];
  const float* Ws = (const float*)d_in[7];
  const float* bs = (const float*)d_in[8];
  const int* idx = (const int*)d_in[9];
  float* out = (float*)d_out;

  char* ws = (char*)d_ws;
  float* E = (float*)ws;                                         // 4 MB
  __hip_bfloat16* h2s = (__hip_bfloat16*)(ws + (size_t)4194304); // 1 MB
  u64* buf1 = (u64*)(ws + (size_t)5242880);                      // 32 KB
  u64* buf2 = (u64*)(ws + (size_t)5275648);                      // 16 KB
  // Election control: tail 64B of `out` (overwritten later by gemm+norm).
  unsigned* ctl = (unsigned*)(out + (size_t)1024 * (NVG + NVS) - 16);

  e_kernel<<<256, 256, 0, stream>>>(X, W1, b1, idx, E, ctl);
  rnn_kernel<<<512, 256, 0, stream>>>(W1, W2, b2, E, buf1, buf2, h2s, ctl);
  gemm_kernel<<<dim3(4, 391), 256, 0, stream>>>(h2s, Wg, bg, out, NVG);
  gemm_kernel<<<dim3(4, 196), 256, 0, stream>>>(h2s, Ws, bs,
                                                out + (size_t)1024 * NVG, NVS);
  norm_kernel<<<2048, 256, 0, stream>>>(out);
}

// Round 8
// 2966.272 us; speedup vs baseline: 1.1389x; 1.1389x over previous
//
#include <hip/hip_runtime.h>
#include <hip/hip_bf16.h>
#include <stdint.h>

#define T_STEPS 1024
#define NH1 1024
#define NH2 512
#define D_IN 300
#define W1_LD 1324
#define W2_LD 1536
#define NVG 50000
#define NVS 25000

typedef unsigned long long u64;
typedef __bf16 bf16x8 __attribute__((ext_vector_type(8)));
typedef short s16x8 __attribute__((ext_vector_type(8)));
typedef float f32x4 __attribute__((ext_vector_type(4)));

// ---------------------------------------------------------------------------
// Kernel 1: E[t][r] = b1[r] + sum_c W1[r][c] * X[idx[t]][c]   (c < 300)
// Also zeroes the 64B election control block (lives in the tail of `out`,
// which gemm/norm overwrite long after the election is done).
// ---------------------------------------------------------------------------
__global__ __launch_bounds__(256) void e_kernel(
    const float* __restrict__ X,
    const float* __restrict__ W1,
    const float* __restrict__ b1,
    const int* __restrict__ idx,
    float* __restrict__ E,
    unsigned* __restrict__ ctl)
{
  if (blockIdx.x == 0 && threadIdx.x < 16) ctl[threadIdx.x] = 0u;

  __shared__ float Xs[32 * 300];
  const int rb = blockIdx.x & 7;
  const int tb = blockIdx.x >> 3;
  const int r0 = rb * 128;
  const int t0 = tb * 32;

  for (int t = 0; t < 32; ++t) {
    int node = idx[t0 + t];
    for (int c = threadIdx.x; c < 300; c += 256)
      Xs[t * 300 + c] = X[(size_t)node * D_IN + c];
  }
  __syncthreads();

  const int rl = threadIdx.x & 127;
  const int th = threadIdx.x >> 7;
  const int tbase = th * 16;
  const int r = r0 + rl;

  float acc[16];
  const float bias = b1[r];
#pragma unroll
  for (int tt = 0; tt < 16; ++tt) acc[tt] = bias;

  const float* wrow = W1 + (size_t)r * W1_LD;
  for (int c0 = 0; c0 < 300; c0 += 4) {
    float w0 = wrow[c0 + 0];
    float w1 = wrow[c0 + 1];
    float w2 = wrow[c0 + 2];
    float w3 = wrow[c0 + 3];
#pragma unroll
    for (int tt = 0; tt < 16; ++tt) {
      const float* xr = Xs + (tbase + tt) * 300 + c0;
      acc[tt] += w0 * xr[0] + w1 * xr[1] + w2 * xr[2] + w3 * xr[3];
    }
  }
#pragma unroll
  for (int tt = 0; tt < 16; ++tt)
    E[(size_t)(t0 + tbase + tt) * NH1 + r] = acc[tt];
}

// ---------------------------------------------------------------------------
// Kernel 2: persistent RNN — SINGLE-XCD team, dirty-L2 handoff, 8-wave blocks.
//
// Protocol (r2-r7 settled): store `sc0` (dirty line in shared XCD L2, never
// HBM); poll `sc0 sc1` every round (the ONLY coherent load — sc0-only,
// buffer_inv+sc0, buffer_inv+plain all fail to observe the dirty line).
//
// New this round — halve broadcast redundancy: 32 blocks x 512 threads
// (8 waves) instead of 64 x 256. Same 256 producer waves / weights / compute
// / stores, but per-step L2 broadcast volume halves (each BLOCK stages
// h1+h2 to LDS once: 32x12KB vs 64x12KB) and each wave polls 3 atoms
// (2 h1 + 1 h2) instead of 6. Theory: per-step time is part coherent-RT,
// part L2 poll-bandwidth contention (64 readers/element); this cuts the
// contention term ~2x. Election threshold 32; deadlock-free (losers exit,
// winners are running when ranked). Tag-in-8B-atom + quad-buffer unchanged.
// ---------------------------------------------------------------------------
__global__ __launch_bounds__(512, 2) void rnn_kernel(
    const float* __restrict__ W1,
    const float* __restrict__ W2,
    const float* __restrict__ b2,
    const float* __restrict__ E,
    u64* __restrict__ buf1,     // [4][1024]
    u64* __restrict__ buf2,     // [4][512]
    __hip_bfloat16* __restrict__ h2s,   // [T][512]
    unsigned* __restrict__ ctl)         // [8] cnt per XCD, [8]=winner
{
  __shared__ float lds1[2][NH1];
  __shared__ float lds2[2][NH2];
  __shared__ int s_role;

  // ---- election: find 32 co-XCD blocks ----
  if (threadIdx.x == 0) {
    int xcd;
    asm volatile("s_getreg_b32 %0, hwreg(HW_REG_XCC_ID)" : "=s"(xcd));
    xcd &= 7;
    unsigned rk = atomicAdd(&ctl[xcd], 1u);
    int role = -1;
    if (rk < 32u) {
      if (rk == 31u) atomicCAS(&ctl[8], 0u, (unsigned)(xcd + 1));
      unsigned wnr;
      while ((wnr = __hip_atomic_load(&ctl[8], __ATOMIC_RELAXED,
                                      __HIP_MEMORY_SCOPE_AGENT)) == 0u)
        __builtin_amdgcn_s_sleep(16);
      if (wnr == (unsigned)(xcd + 1)) role = (int)rk;
    }
    s_role = role;
  }
  __syncthreads();
  if (s_role < 0) return;
  const int b = s_role;                           // 0..31, all on one XCD

  const int lane = threadIdx.x & 63;
  const int w = threadIdx.x >> 6;                 // wave in block, 0..7
  const int wvid = b * 8 + w;                     // 0..255
  const int r1 = wvid * 4;
  const int r2 = wvid * 2;
  const int oct = (w + b) & 7;                    // polled octant (staggered)

  float w1r[4][16];
#pragma unroll
  for (int i = 0; i < 4; ++i)
#pragma unroll
    for (int j = 0; j < 16; ++j)
      w1r[i][j] = W1[(size_t)(r1 + i) * W1_LD + D_IN + lane + 64 * j];

  float w2r[2][24];
#pragma unroll
  for (int i = 0; i < 2; ++i)
#pragma unroll
    for (int j = 0; j < 24; ++j)
      w2r[i][j] = W2[(size_t)(r2 + i) * W2_LD + lane + 64 * j];

  const float b2a = b2[r2];
  const float b2b = b2[r2 + 1];

  for (int s = 0; s <= T_STEPS; ++s) {
    // Prefetch E for this step's h1 rows (latency overlaps the spin).
    float ev = 0.f;
    if (s < T_STEPS) ev = E[(size_t)s * NH1 + r1 + (lane & 3)];

    // ---- poll my octant of h1(s) (2 atoms) and h2(s-1) (1 atom) ----
    float v1[2] = {0.f, 0.f};
    float v2 = 0.f;
    unsigned miss = 0;
    if (s >= 1) miss |= 0x3u;
    if (s >= 2) miss |= 0x4u;
    const u64* p1 = buf1 + (size_t)(s & 3) * NH1 + 128 * oct + lane;
    const u64* p2 = buf2 + (size_t)((s - 1) & 3) * NH2 + 64 * oct + lane;
    const unsigned tag1 = (unsigned)s;
    const unsigned tag2 = (unsigned)(s - 1);

    while (miss) {
      u64 t1[2], t2;
      asm volatile(
          "global_load_dwordx2 %0, %3, off sc0 sc1\n\t"
          "global_load_dwordx2 %1, %3, off offset:512 sc0 sc1\n\t"
          "global_load_dwordx2 %2, %4, off sc0 sc1\n\t"
          "s_waitcnt vmcnt(0)"
          : "=&v"(t1[0]), "=&v"(t1[1]), "=&v"(t2)
          : "v"(p1), "v"(p2)
          : "memory");
#pragma unroll
      for (int j = 0; j < 2; ++j)
        if ((miss & (1u << j)) && (unsigned)(t1[j] >> 32) == tag1) {
          v1[j] = __uint_as_float((unsigned)t1[j]);
          miss &= ~(1u << j);
        }
      if ((miss & 0x4u) && (unsigned)(t2 >> 32) == tag2) {
        v2 = __uint_as_float((unsigned)t2);
        miss &= ~0x4u;
      }
    }

    // ---- publish octant to LDS, barrier ----
    const int pb = s & 1;
#pragma unroll
    for (int j = 0; j < 2; ++j) lds1[pb][128 * oct + 64 * j + lane] = v1[j];
    lds2[pb][64 * oct + lane] = v2;
    __syncthreads();

    // ---- compute from LDS ----
    float a0 = 0.f, a1 = 0.f, a2 = 0.f, a3 = 0.f, a4 = 0.f, a5 = 0.f;
#pragma unroll
    for (int j = 0; j < 16; ++j) {
      float h = lds1[pb][lane + 64 * j];
      a0 += w1r[0][j] * h;
      a1 += w1r[1][j] * h;
      a2 += w1r[2][j] * h;
      a3 += w1r[3][j] * h;
      a4 += w2r[0][j] * h;
      a5 += w2r[1][j] * h;
    }
#pragma unroll
    for (int j = 0; j < 8; ++j) {
      float h = lds2[pb][lane + 64 * j];
      a4 += w2r[0][16 + j] * h;
      a5 += w2r[1][16 + j] * h;
    }

    // h1 critical path first: reduce a0..a3, store into shared L2 (sc0).
#pragma unroll
    for (int off = 32; off; off >>= 1) {
      a0 += __shfl_xor(a0, off);
      a1 += __shfl_xor(a1, off);
      a2 += __shfl_xor(a2, off);
      a3 += __shfl_xor(a3, off);
    }
    if (s < T_STEPS && lane < 4) {
      float x = (lane == 0 ? a0 : lane == 1 ? a1 : lane == 2 ? a2 : a3) + ev;
      float h = x > 0.f ? x : 0.01f * x;
      u64 pk = ((u64)(unsigned)(s + 1) << 32) | (u64)__float_as_uint(h);
      u64* dst = buf1 + (size_t)((s + 1) & 3) * NH1 + r1 + lane;
      asm volatile("global_store_dwordx2 %0, %1, off sc0"
                   :: "v"(dst), "v"(pk) : "memory");
    }

    // h2 off the critical path.
    if (s >= 1) {
#pragma unroll
      for (int off = 32; off; off >>= 1) {
        a4 += __shfl_xor(a4, off);
        a5 += __shfl_xor(a5, off);
      }
      if (lane >= 4 && lane < 6) {
        int i = lane - 4;
        float x = (i == 0 ? a4 : a5) + (i == 0 ? b2a : b2b);
        float h = x > 0.f ? x : 0.01f * x;
        u64 pk = ((u64)(unsigned)s << 32) | (u64)__float_as_uint(h);
        u64* dst = buf2 + (size_t)(s & 3) * NH2 + r2 + i;
        asm volatile("global_store_dwordx2 %0, %1, off sc0"
                     :: "v"(dst), "v"(pk) : "memory");
        h2s[(size_t)(s - 1) * NH2 + r2 + i] = __float2bfloat16(h);
      }
    }
  }
}

// ---------------------------------------------------------------------------
// Kernel 3: C[m][n] = sum_k A[m][k]*B[n][k] + bias[n]  (fp32 logits out).
// A = h2s [1024][512] bf16. B fp32 -> bf16 while staging. 256x128x64 tiles.
// ---------------------------------------------------------------------------
__global__ __launch_bounds__(256, 1) void gemm_kernel(
    const __hip_bfloat16* __restrict__ A,
    const float* __restrict__ B,
    const float* __restrict__ bias,
    float* __restrict__ C,
    int N)
{
  __shared__ short As[256 * 64];
  __shared__ short Bs[128 * 64];
  const int tid = threadIdx.x;
  const int lane = tid & 63;
  const int wv = tid >> 6;
  const int wm = (wv & 1) * 128;
  const int wn = (wv >> 1) * 64;
  const int m0 = blockIdx.x * 256;
  const int n0 = blockIdx.y * 128;
  const int ml = lane & 15;
  const int kq = lane >> 4;

  f32x4 acc[8][4];
#pragma unroll
  for (int i = 0; i < 8; ++i)
#pragma unroll
    for (int j = 0; j < 4; ++j)
      acc[i][j] = (f32x4){0.f, 0.f, 0.f, 0.f};

  for (int kb = 0; kb < 512; kb += 64) {
    __syncthreads();
#pragma unroll
    for (int q = 0; q < 8; ++q) {
      int ch = q * 256 + tid;
      int row = ch >> 3;
      int kc = ch & 7;
      int phys = kc ^ (row & 7);
      s16x8 av = *(const s16x8*)((const short*)A + (size_t)(m0 + row) * 512 + kb + kc * 8);
      *(s16x8*)(As + row * 64 + phys * 8) = av;
    }
#pragma unroll
    for (int q = 0; q < 4; ++q) {
      int ch = q * 256 + tid;
      int row = ch >> 3;
      int kc = ch & 7;
      int phys = kc ^ (row & 7);
      int gr = n0 + row;
      if (gr >= N) gr = N - 1;
      const float* src = B + (size_t)gr * 512 + kb + kc * 8;
      f32x4 f0 = *(const f32x4*)(src);
      f32x4 f1 = *(const f32x4*)(src + 4);
      bf16x8 bv;
      bv[0] = (__bf16)f0[0]; bv[1] = (__bf16)f0[1];
      bv[2] = (__bf16)f0[2]; bv[3] = (__bf16)f0[3];
      bv[4] = (__bf16)f1[0]; bv[5] = (__bf16)f1[1];
      bv[6] = (__bf16)f1[2]; bv[7] = (__bf16)f1[3];
      *(bf16x8*)(Bs + row * 64 + phys * 8) = bv;
    }
    __syncthreads();
#pragma unroll
    for (int ks = 0; ks < 2; ++ks) {
      bf16x8 af[8], bfr[4];
#pragma unroll
      for (int i = 0; i < 8; ++i) {
        int row = wm + 16 * i + ml;
        int phys = (ks * 4 + kq) ^ (row & 7);
        af[i] = *(const bf16x8*)(As + row * 64 + phys * 8);
      }
#pragma unroll
      for (int j = 0; j < 4; ++j) {
        int row = wn + 16 * j + ml;
        int phys = (ks * 4 + kq) ^ (row & 7);
        bfr[j] = *(const bf16x8*)(Bs + row * 64 + phys * 8);
      }
#pragma unroll
      for (int i = 0; i < 8; ++i)
#pragma unroll
        for (int j = 0; j < 4; ++j)
          acc[i][j] = __builtin_amdgcn_mfma_f32_16x16x32_bf16(af[i], bfr[j], acc[i][j], 0, 0, 0);
    }
  }

  float bv[4];
#pragma unroll
  for (int j = 0; j < 4; ++j) {
    int n = n0 + wn + 16 * j + ml;
    bv[j] = (n < N) ? bias[n] : 0.f;
  }
#pragma unroll
  for (int i = 0; i < 8; ++i) {
    int mrow = m0 + wm + 16 * i + kq * 4;
#pragma unroll
    for (int j = 0; j < 4; ++j) {
      int n = n0 + wn + 16 * j + ml;
      if (n < N) {
#pragma unroll
        for (int r = 0; r < 4; ++r)
          C[(size_t)(mrow + r) * N + n] = acc[i][j][r] + bv[j];
      }
    }
  }
}

// ---------------------------------------------------------------------------
// Kernel 4: in-place fp32 log-softmax per (row, segment). 2048 blocks x 256.
// ---------------------------------------------------------------------------
__global__ __launch_bounds__(256) void norm_kernel(float* __restrict__ out)
{
  const int b = blockIdx.x;
  const int t = b & 1023;
  const int seg = b >> 10;
  const size_t base = seg == 0 ? (size_t)t * NVG
                               : (size_t)1024 * NVG + (size_t)t * NVS;
  const int len = seg == 0 ? NVG : NVS;
  float* p = out + base;
  const int lane = threadIdx.x & 63;
  const int wv = threadIdx.x >> 6;
  __shared__ float red[4];

  float m = -3.0e38f;
  for (int i = threadIdx.x; i < len; i += 256)
    m = fmaxf(m, p[i]);
#pragma unroll
  for (int off = 32; off; off >>= 1) m = fmaxf(m, __shfl_xor(m, off));
  if (lane == 0) red[wv] = m;
  __syncthreads();
  m = fmaxf(fmaxf(red[0], red[1]), fmaxf(red[2], red[3]));
  __syncthreads();

  float sum = 0.f;
  for (int i = threadIdx.x; i < len; i += 256)
    sum += expf(p[i] - m);
#pragma unroll
  for (int off = 32; off; off >>= 1) sum += __shfl_xor(sum, off);
  if (lane == 0) red[wv] = sum;
  __syncthreads();
  sum = red[0] + red[1] + red[2] + red[3];
  const float lse = m + logf(sum);

  for (int i = threadIdx.x; i < len; i += 256)
    p[i] = p[i] - lse;
}

// ---------------------------------------------------------------------------
extern "C" void kernel_launch(void* const* d_in, const int* in_sizes, int n_in,
                              void* d_out, int out_size, void* d_ws, size_t ws_size,
                              hipStream_t stream) {
  const float* X  = (const float*)d_in[0];
  const float* W1 = (const float*)d_in[1];
  const float* b1 = (const float*)d_in[2];
  const float* W2 = (const float*)d_in[3];
  const float* b2 = (const float*)d_in[4];
  const float* Wg = (const float*)d_in[5];
  const float* bg = (const float*)d_in[6];
  const float* Ws = (const float*)d_in[7];
  const float* bs = (const float*)d_in[8];
  const int* idx = (const int*)d_in[9];
  float* out = (float*)d_out;

  char* ws = (char*)d_ws;
  float* E = (float*)ws;                                         // 4 MB
  __hip_bfloat16* h2s = (__hip_bfloat16*)(ws + (size_t)4194304); // 1 MB
  u64* buf1 = (u64*)(ws + (size_t)5242880);                      // 32 KB
  u64* buf2 = (u64*)(ws + (size_t)5275648);                      // 16 KB
  // Election control: tail 64B of `out` (overwritten later by gemm+norm).
  unsigned* ctl = (unsigned*)(out + (size_t)1024 * (NVG + NVS) - 16);

  e_kernel<<<256, 256, 0, stream>>>(X, W1, b1, idx, E, ctl);
  rnn_kernel<<<256, 512, 0, stream>>>(W1, W2, b2, E, buf1, buf2, h2s, ctl);
  gemm_kernel<<<dim3(4, 391), 256, 0, stream>>>(h2s, Wg, bg, out, NVG);
  gemm_kernel<<<dim3(4, 196), 256, 0, stream>>>(h2s, Ws, bs,
                                                out + (size_t)1024 * NVG, NVS);
  norm_kernel<<<2048, 256, 0, stream>>>(out);
}

// Round 9
// 2930.509 us; speedup vs baseline: 1.1528x; 1.0122x over previous
//
#include <hip/hip_runtime.h>
#include <hip/hip_bf16.h>
#include <stdint.h>

#define T_STEPS 1024
#define NH1 1024
#define NH2 512
#define D_IN 300
#define W1_LD 1324
#define W2_LD 1536
#define NVG 50000
#define NVS 25000

typedef unsigned long long u64;
typedef __bf16 bf16x8 __attribute__((ext_vector_type(8)));
typedef short s16x8 __attribute__((ext_vector_type(8)));
typedef float f32x4 __attribute__((ext_vector_type(4)));

// ---------------------------------------------------------------------------
// Kernel 1: E[t][r] = b1[r] + sum_c W1[r][c] * X[idx[t]][c]   (c < 300)
// Also zeroes the 64B election control block (lives in the tail of `out`,
// which gemm/norm overwrite long after the election is done).
// ---------------------------------------------------------------------------
__global__ __launch_bounds__(256) void e_kernel(
    const float* __restrict__ X,
    const float* __restrict__ W1,
    const float* __restrict__ b1,
    const int* __restrict__ idx,
    float* __restrict__ E,
    unsigned* __restrict__ ctl)
{
  if (blockIdx.x == 0 && threadIdx.x < 16) ctl[threadIdx.x] = 0u;

  __shared__ float Xs[32 * 300];
  const int rb = blockIdx.x & 7;
  const int tb = blockIdx.x >> 3;
  const int r0 = rb * 128;
  const int t0 = tb * 32;

  for (int t = 0; t < 32; ++t) {
    int node = idx[t0 + t];
    for (int c = threadIdx.x; c < 300; c += 256)
      Xs[t * 300 + c] = X[(size_t)node * D_IN + c];
  }
  __syncthreads();

  const int rl = threadIdx.x & 127;
  const int th = threadIdx.x >> 7;
  const int tbase = th * 16;
  const int r = r0 + rl;

  float acc[16];
  const float bias = b1[r];
#pragma unroll
  for (int tt = 0; tt < 16; ++tt) acc[tt] = bias;

  const float* wrow = W1 + (size_t)r * W1_LD;
  for (int c0 = 0; c0 < 300; c0 += 4) {
    float w0 = wrow[c0 + 0];
    float w1 = wrow[c0 + 1];
    float w2 = wrow[c0 + 2];
    float w3 = wrow[c0 + 3];
#pragma unroll
    for (int tt = 0; tt < 16; ++tt) {
      const float* xr = Xs + (tbase + tt) * 300 + c0;
      acc[tt] += w0 * xr[0] + w1 * xr[1] + w2 * xr[2] + w3 * xr[3];
    }
  }
#pragma unroll
  for (int tt = 0; tt < 16; ++tt)
    E[(size_t)(t0 + tbase + tt) * NH1 + r] = acc[tt];
}

// ---------------------------------------------------------------------------
// Kernel 2: persistent RNN — SINGLE-XCD team, dirty-L2 handoff, 8-wave
// blocks (r8 champion structure) + 2-deep PIPELINED polling.
//
// Protocol (r2-r7 settled): store `sc0` (dirty line in shared XCD L2, never
// HBM); poll `sc0 sc1` every round (the ONLY coherent load).
//
// New: instead of {issue 3 loads, vmcnt(0), check} (detect up to 2xRT after
// visibility), keep TWO 3-load batches in flight and check them alternately
// with vmcnt(3) -> average detection ~1xRT. Stale-register reads are
// harmless (old tags never match); sched_barrier(0) after each wait stops
// the compiler hoisting checks above the wait (guide rule #18).
// ---------------------------------------------------------------------------
#define PISSUE(T)                                                            \
  asm volatile(                                                              \
      "global_load_dwordx2 %0, %3, off sc0 sc1\n\t"                          \
      "global_load_dwordx2 %1, %3, off offset:512 sc0 sc1\n\t"               \
      "global_load_dwordx2 %2, %4, off sc0 sc1"                              \
      : "=&v"(T[0]), "=&v"(T[1]), "=&v"(T[2])                                \
      : "v"(p1), "v"(p2)                                                     \
      : "memory")
#define PWAIT3                                                               \
  do {                                                                       \
    asm volatile("s_waitcnt vmcnt(3)" ::: "memory");                         \
    __builtin_amdgcn_sched_barrier(0);                                       \
  } while (0)
#define PCHECK(T)                                                            \
  do {                                                                       \
    if ((miss & 0x1u) && (unsigned)(T[0] >> 32) == tag1) {                   \
      v1[0] = __uint_as_float((unsigned)T[0]); miss &= ~0x1u; }              \
    if ((miss & 0x2u) && (unsigned)(T[1] >> 32) == tag1) {                   \
      v1[1] = __uint_as_float((unsigned)T[1]); miss &= ~0x2u; }              \
    if ((miss & 0x4u) && (unsigned)(T[2] >> 32) == tag2) {                   \
      v2 = __uint_as_float((unsigned)T[2]); miss &= ~0x4u; }                 \
  } while (0)

__global__ __launch_bounds__(512, 2) void rnn_kernel(
    const float* __restrict__ W1,
    const float* __restrict__ W2,
    const float* __restrict__ b2,
    const float* __restrict__ E,
    u64* __restrict__ buf1,     // [4][1024]
    u64* __restrict__ buf2,     // [4][512]
    __hip_bfloat16* __restrict__ h2s,   // [T][512]
    unsigned* __restrict__ ctl)         // [8] cnt per XCD, [8]=winner
{
  __shared__ float lds1[2][NH1];
  __shared__ float lds2[2][NH2];
  __shared__ int s_role;

  // ---- election: find 32 co-XCD blocks ----
  if (threadIdx.x == 0) {
    int xcd;
    asm volatile("s_getreg_b32 %0, hwreg(HW_REG_XCC_ID)" : "=s"(xcd));
    xcd &= 7;
    unsigned rk = atomicAdd(&ctl[xcd], 1u);
    int role = -1;
    if (rk < 32u) {
      if (rk == 31u) atomicCAS(&ctl[8], 0u, (unsigned)(xcd + 1));
      unsigned wnr;
      while ((wnr = __hip_atomic_load(&ctl[8], __ATOMIC_RELAXED,
                                      __HIP_MEMORY_SCOPE_AGENT)) == 0u)
        __builtin_amdgcn_s_sleep(16);
      if (wnr == (unsigned)(xcd + 1)) role = (int)rk;
    }
    s_role = role;
  }
  __syncthreads();
  if (s_role < 0) return;
  const int b = s_role;                           // 0..31, all on one XCD

  const int lane = threadIdx.x & 63;
  const int w = threadIdx.x >> 6;                 // wave in block, 0..7
  const int wvid = b * 8 + w;                     // 0..255
  const int r1 = wvid * 4;
  const int r2 = wvid * 2;
  const int oct = (w + b) & 7;                    // polled octant (staggered)

  float w1r[4][16];
#pragma unroll
  for (int i = 0; i < 4; ++i)
#pragma unroll
    for (int j = 0; j < 16; ++j)
      w1r[i][j] = W1[(size_t)(r1 + i) * W1_LD + D_IN + lane + 64 * j];

  float w2r[2][24];
#pragma unroll
  for (int i = 0; i < 2; ++i)
#pragma unroll
    for (int j = 0; j < 24; ++j)
      w2r[i][j] = W2[(size_t)(r2 + i) * W2_LD + lane + 64 * j];

  const float b2a = b2[r2];
  const float b2b = b2[r2 + 1];

  for (int s = 0; s <= T_STEPS; ++s) {
    // Prefetch E for this step's h1 rows (latency overlaps the spin).
    float ev = 0.f;
    if (s < T_STEPS) ev = E[(size_t)s * NH1 + r1 + (lane & 3)];

    // ---- pipelined poll of my octant: h1(s) (2 atoms) + h2(s-1) (1) ----
    float v1[2] = {0.f, 0.f};
    float v2 = 0.f;
    unsigned miss = 0;
    if (s >= 1) miss |= 0x3u;
    if (s >= 2) miss |= 0x4u;
    const u64* p1 = buf1 + (size_t)(s & 3) * NH1 + 128 * oct + lane;
    const u64* p2 = buf2 + (size_t)((s - 1) & 3) * NH2 + 64 * oct + lane;
    const unsigned tag1 = (unsigned)s;
    const unsigned tag2 = (unsigned)(s - 1);

    if (miss) {
      u64 tA[3], tB[3];
      PISSUE(tA);
      for (;;) {
        PISSUE(tB);
        PWAIT3;            // tA complete (drains prior stores + ev too)
        PCHECK(tA);
        if (!miss) break;
        PISSUE(tA);
        PWAIT3;            // tB complete
        PCHECK(tB);
        if (!miss) break;
      }
      asm volatile("s_waitcnt vmcnt(0)" ::: "memory");  // drain other batch
    }

    // ---- publish octant to LDS, barrier ----
    const int pb = s & 1;
#pragma unroll
    for (int j = 0; j < 2; ++j) lds1[pb][128 * oct + 64 * j + lane] = v1[j];
    lds2[pb][64 * oct + lane] = v2;
    __syncthreads();

    // ---- compute from LDS ----
    float a0 = 0.f, a1 = 0.f, a2 = 0.f, a3 = 0.f, a4 = 0.f, a5 = 0.f;
#pragma unroll
    for (int j = 0; j < 16; ++j) {
      float h = lds1[pb][lane + 64 * j];
      a0 += w1r[0][j] * h;
      a1 += w1r[1][j] * h;
      a2 += w1r[2][j] * h;
      a3 += w1r[3][j] * h;
      a4 += w2r[0][j] * h;
      a5 += w2r[1][j] * h;
    }
#pragma unroll
    for (int j = 0; j < 8; ++j) {
      float h = lds2[pb][lane + 64 * j];
      a4 += w2r[0][16 + j] * h;
      a5 += w2r[1][16 + j] * h;
    }

    // h1 critical path first: reduce a0..a3, store into shared L2 (sc0).
#pragma unroll
    for (int off = 32; off; off >>= 1) {
      a0 += __shfl_xor(a0, off);
      a1 += __shfl_xor(a1, off);
      a2 += __shfl_xor(a2, off);
      a3 += __shfl_xor(a3, off);
    }
    if (s < T_STEPS && lane < 4) {
      float x = (lane == 0 ? a0 : lane == 1 ? a1 : lane == 2 ? a2 : a3) + ev;
      float h = x > 0.f ? x : 0.01f * x;
      u64 pk = ((u64)(unsigned)(s + 1) << 32) | (u64)__float_as_uint(h);
      u64* dst = buf1 + (size_t)((s + 1) & 3) * NH1 + r1 + lane;
      asm volatile("global_store_dwordx2 %0, %1, off sc0"
                   :: "v"(dst), "v"(pk) : "memory");
    }

    // h2 off the critical path.
    if (s >= 1) {
#pragma unroll
      for (int off = 32; off; off >>= 1) {
        a4 += __shfl_xor(a4, off);
        a5 += __shfl_xor(a5, off);
      }
      if (lane >= 4 && lane < 6) {
        int i = lane - 4;
        float x = (i == 0 ? a4 : a5) + (i == 0 ? b2a : b2b);
        float h = x > 0.f ? x : 0.01f * x;
        u64 pk = ((u64)(unsigned)s << 32) | (u64)__float_as_uint(h);
        u64* dst = buf2 + (size_t)(s & 3) * NH2 + r2 + i;
        asm volatile("global_store_dwordx2 %0, %1, off sc0"
                     :: "v"(dst), "v"(pk) : "memory");
        h2s[(size_t)(s - 1) * NH2 + r2 + i] = __float2bfloat16(h);
      }
    }
  }
}

// ---------------------------------------------------------------------------
// Kernel 2.5: one-time fp32 -> bf16 weight conversion (grid-stride, 8/thread)
// ---------------------------------------------------------------------------
__global__ __launch_bounds__(256) void bconv_kernel(
    const float* __restrict__ B, __hip_bfloat16* __restrict__ Bb, int n8)
{
  int stride = gridDim.x * 256;
  for (int i = blockIdx.x * 256 + threadIdx.x; i < n8; i += stride) {
    const f32x4* s = (const f32x4*)B + (size_t)i * 2;
    f32x4 f0 = s[0], f1 = s[1];
    bf16x8 bv;
    bv[0] = (__bf16)f0[0]; bv[1] = (__bf16)f0[1];
    bv[2] = (__bf16)f0[2]; bv[3] = (__bf16)f0[3];
    bv[4] = (__bf16)f1[0]; bv[5] = (__bf16)f1[1];
    bv[6] = (__bf16)f1[2]; bv[7] = (__bf16)f1[3];
    *(bf16x8*)((short*)Bb + (size_t)i * 8) = bv;
  }
}

// ---------------------------------------------------------------------------
// Kernel 3a: GEMM with pre-converted bf16 B (B staging = pure 16B copies).
// C[m][n] = sum_k A[m][k]*B[n][k] + bias[n]. 256x128x64 tiles.
// ---------------------------------------------------------------------------
__global__ __launch_bounds__(256, 1) void gemm_bf16_kernel(
    const __hip_bfloat16* __restrict__ A,
    const __hip_bfloat16* __restrict__ Bb,
    const float* __restrict__ bias,
    float* __restrict__ C,
    int N)
{
  __shared__ short As[256 * 64];
  __shared__ short Bs[128 * 64];
  const int tid = threadIdx.x;
  const int lane = tid & 63;
  const int wv = tid >> 6;
  const int wm = (wv & 1) * 128;
  const int wn = (wv >> 1) * 64;
  const int m0 = blockIdx.x * 256;
  const int n0 = blockIdx.y * 128;
  const int ml = lane & 15;
  const int kq = lane >> 4;

  f32x4 acc[8][4];
#pragma unroll
  for (int i = 0; i < 8; ++i)
#pragma unroll
    for (int j = 0; j < 4; ++j)
      acc[i][j] = (f32x4){0.f, 0.f, 0.f, 0.f};

  for (int kb = 0; kb < 512; kb += 64) {
    __syncthreads();
#pragma unroll
    for (int q = 0; q < 8; ++q) {
      int ch = q * 256 + tid;
      int row = ch >> 3;
      int kc = ch & 7;
      int phys = kc ^ (row & 7);
      s16x8 av = *(const s16x8*)((const short*)A + (size_t)(m0 + row) * 512 + kb + kc * 8);
      *(s16x8*)(As + row * 64 + phys * 8) = av;
    }
#pragma unroll
    for (int q = 0; q < 4; ++q) {
      int ch = q * 256 + tid;
      int row = ch >> 3;
      int kc = ch & 7;
      int phys = kc ^ (row & 7);
      int gr = n0 + row;
      if (gr >= N) gr = N - 1;
      s16x8 bvv = *(const s16x8*)((const short*)Bb + (size_t)gr * 512 + kb + kc * 8);
      *(s16x8*)(Bs + row * 64 + phys * 8) = bvv;
    }
    __syncthreads();
#pragma unroll
    for (int ks = 0; ks < 2; ++ks) {
      bf16x8 af[8], bfr[4];
#pragma unroll
      for (int i = 0; i < 8; ++i) {
        int row = wm + 16 * i + ml;
        int phys = (ks * 4 + kq) ^ (row & 7);
        af[i] = *(const bf16x8*)(As + row * 64 + phys * 8);
      }
#pragma unroll
      for (int j = 0; j < 4; ++j) {
        int row = wn + 16 * j + ml;
        int phys = (ks * 4 + kq) ^ (row & 7);
        bfr[j] = *(const bf16x8*)(Bs + row * 64 + phys * 8);
      }
#pragma unroll
      for (int i = 0; i < 8; ++i)
#pragma unroll
        for (int j = 0; j < 4; ++j)
          acc[i][j] = __builtin_amdgcn_mfma_f32_16x16x32_bf16(af[i], bfr[j], acc[i][j], 0, 0, 0);
    }
  }

  float bv[4];
#pragma unroll
  for (int j = 0; j < 4; ++j) {
    int n = n0 + wn + 16 * j + ml;
    bv[j] = (n < N) ? bias[n] : 0.f;
  }
#pragma unroll
  for (int i = 0; i < 8; ++i) {
    int mrow = m0 + wm + 16 * i + kq * 4;
#pragma unroll
    for (int j = 0; j < 4; ++j) {
      int n = n0 + wn + 16 * j + ml;
      if (n < N) {
#pragma unroll
        for (int r = 0; r < 4; ++r)
          C[(size_t)(mrow + r) * N + n] = acc[i][j][r] + bv[j];
      }
    }
  }
}

// ---------------------------------------------------------------------------
// Kernel 3b: fallback GEMM with fp32 B converted during staging (r8 path,
// used only if the workspace is too small for the pre-converted copies).
// ---------------------------------------------------------------------------
__global__ __launch_bounds__(256, 1) void gemm_kernel(
    const __hip_bfloat16* __restrict__ A,
    const float* __restrict__ B,
    const float* __restrict__ bias,
    float* __restrict__ C,
    int N)
{
  __shared__ short As[256 * 64];
  __shared__ short Bs[128 * 64];
  const int tid = threadIdx.x;
  const int lane = tid & 63;
  const int wv = tid >> 6;
  const int wm = (wv & 1) * 128;
  const int wn = (wv >> 1) * 64;
  const int m0 = blockIdx.x * 256;
  const int n0 = blockIdx.y * 128;
  const int ml = lane & 15;
  const int kq = lane >> 4;

  f32x4 acc[8][4];
#pragma unroll
  for (int i = 0; i < 8; ++i)
#pragma unroll
    for (int j = 0; j < 4; ++j)
      acc[i][j] = (f32x4){0.f, 0.f, 0.f, 0.f};

  for (int kb = 0; kb < 512; kb += 64) {
    __syncthreads();
#pragma unroll
    for (int q = 0; q < 8; ++q) {
      int ch = q * 256 + tid;
      int row = ch >> 3;
      int kc = ch & 7;
      int phys = kc ^ (row & 7);
      s16x8 av = *(const s16x8*)((const short*)A + (size_t)(m0 + row) * 512 + kb + kc * 8);
      *(s16x8*)(As + row * 64 + phys * 8) = av;
    }
#pragma unroll
    for (int q = 0; q < 4; ++q) {
      int ch = q * 256 + tid;
      int row = ch >> 3;
      int kc = ch & 7;
      int phys = kc ^ (row & 7);
      int gr = n0 + row;
      if (gr >= N) gr = N - 1;
      const float* src = B + (size_t)gr * 512 + kb + kc * 8;
      f32x4 f0 = *(const f32x4*)(src);
      f32x4 f1 = *(const f32x4*)(src + 4);
      bf16x8 bv;
      bv[0] = (__bf16)f0[0]; bv[1] = (__bf16)f0[1];
      bv[2] = (__bf16)f0[2]; bv[3] = (__bf16)f0[3];
      bv[4] = (__bf16)f1[0]; bv[5] = (__bf16)f1[1];
      bv[6] = (__bf16)f1[2]; bv[7] = (__bf16)f1[3];
      *(bf16x8*)(Bs + row * 64 + phys * 8) = bv;
    }
    __syncthreads();
#pragma unroll
    for (int ks = 0; ks < 2; ++ks) {
      bf16x8 af[8], bfr[4];
#pragma unroll
      for (int i = 0; i < 8; ++i) {
        int row = wm + 16 * i + ml;
        int phys = (ks * 4 + kq) ^ (row & 7);
        af[i] = *(const bf16x8*)(As + row * 64 + phys * 8);
      }
#pragma unroll
      for (int j = 0; j < 4; ++j) {
        int row = wn + 16 * j + ml;
        int phys = (ks * 4 + kq) ^ (row & 7);
        bfr[j] = *(const bf16x8*)(Bs + row * 64 + phys * 8);
      }
#pragma unroll
      for (int i = 0; i < 8; ++i)
#pragma unroll
        for (int j = 0; j < 4; ++j)
          acc[i][j] = __builtin_amdgcn_mfma_f32_16x16x32_bf16(af[i], bfr[j], acc[i][j], 0, 0, 0);
    }
  }

  float bv[4];
#pragma unroll
  for (int j = 0; j < 4; ++j) {
    int n = n0 + wn + 16 * j + ml;
    bv[j] = (n < N) ? bias[n] : 0.f;
  }
#pragma unroll
  for (int i = 0; i < 8; ++i) {
    int mrow = m0 + wm + 16 * i + kq * 4;
#pragma unroll
    for (int j = 0; j < 4; ++j) {
      int n = n0 + wn + 16 * j + ml;
      if (n < N) {
#pragma unroll
        for (int r = 0; r < 4; ++r)
          C[(size_t)(mrow + r) * N + n] = acc[i][j][r] + bv[j];
      }
    }
  }
}

// ---------------------------------------------------------------------------
// Kernel 4: in-place fp32 log-softmax per (row, segment).
// 2-pass online-LSE (was 3-pass), f32x4 vectorized, 512 threads.
// ---------------------------------------------------------------------------
__global__ __launch_bounds__(512) void norm_kernel(float* __restrict__ out)
{
  const int b = blockIdx.x;
  const int t = b & 1023;
  const int seg = b >> 10;
  const size_t base = seg == 0 ? (size_t)t * NVG
                               : (size_t)1024 * NVG + (size_t)t * NVS;
  const int len4 = (seg == 0 ? NVG : NVS) >> 2;
  f32x4* p = (f32x4*)(out + base);
  const int lane = threadIdx.x & 63;
  const int wv = threadIdx.x >> 6;
  __shared__ float redm[8], reds[8];

  // Pass 1: online (max, sum-exp) per thread.
  float m = -3.0e38f, ssum = 0.f;
  for (int i = threadIdx.x; i < len4; i += 512) {
    f32x4 v = p[i];
    float vm = fmaxf(fmaxf(v[0], v[1]), fmaxf(v[2], v[3]));
    if (vm > m) { ssum *= expf(m - vm); m = vm; }
    ssum += expf(v[0] - m) + expf(v[1] - m) + expf(v[2] - m) + expf(v[3] - m);
  }
#pragma unroll
  for (int off = 32; off; off >>= 1) {
    float mo = __shfl_xor(m, off);
    float so = __shfl_xor(ssum, off);
    float mn = fmaxf(m, mo);
    ssum = ssum * expf(m - mn) + so * expf(mo - mn);
    m = mn;
  }
  if (lane == 0) { redm[wv] = m; reds[wv] = ssum; }
  __syncthreads();
  float M = redm[0], S = reds[0];
#pragma unroll
  for (int k = 1; k < 8; ++k) {
    float mo = redm[k], so = reds[k];
    float mn = fmaxf(M, mo);
    S = S * expf(M - mn) + so * expf(mo - mn);
    M = mn;
  }
  const float lse = M + logf(S);

  // Pass 2: subtract.
  for (int i = threadIdx.x; i < len4; i += 512) {
    f32x4 v = p[i];
    v[0] -= lse; v[1] -= lse; v[2] -= lse; v[3] -= lse;
    p[i] = v;
  }
}

// ---------------------------------------------------------------------------
extern "C" void kernel_launch(void* const* d_in, const int* in_sizes, int n_in,
                              void* d_out, int out_size, void* d_ws, size_t ws_size,
                              hipStream_t stream) {
  const float* X  = (const float*)d_in[0];
  const float* W1 = (const float*)d_in[1];
  const float* b1 = (const float*)d_in[2];
  const float* W2 = (const float*)d_in[3];
  const float* b2 = (const float*)d_in[4];
  const float* Wg = (const float*)d_in[5];
  const float* bg = (const float*)d_in[6];
  const float* Ws = (const float*)d_in[7];
  const float* bs = (const float*)d_in[8];
  const int* idx = (const int*)d_in[9];
  float* out = (float*)d_out;

  char* ws = (char*)d_ws;
  float* E = (float*)ws;                                         // 4 MB
  __hip_bfloat16* h2s = (__hip_bfloat16*)(ws + (size_t)4194304); // 1 MB
  u64* buf1 = (u64*)(ws + (size_t)5242880);                      // 32 KB
  u64* buf2 = (u64*)(ws + (size_t)5275648);                      // 16 KB
  // bf16 weight copies (gated on workspace size):
  __hip_bfloat16* Wgb = (__hip_bfloat16*)(ws + (size_t)8388608);        // 51.2 MB
  __hip_bfloat16* Wsb = (__hip_bfloat16*)(ws + (size_t)59588608);       // 25.6 MB
  const bool big_ws = ws_size >= (size_t)85200000;
  // Election control: tail 64B of `out` (overwritten later by gemm+norm).
  unsigned* ctl = (unsigned*)(out + (size_t)1024 * (NVG + NVS) - 16);

  e_kernel<<<256, 256, 0, stream>>>(X, W1, b1, idx, E, ctl);
  rnn_kernel<<<256, 512, 0, stream>>>(W1, W2, b2, E, buf1, buf2, h2s, ctl);
  if (big_ws) {
    bconv_kernel<<<2048, 256, 0, stream>>>(Wg, Wgb, NVG * 512 / 8);
    bconv_kernel<<<2048, 256, 0, stream>>>(Ws, Wsb, NVS * 512 / 8);
    gemm_bf16_kernel<<<dim3(4, 391), 256, 0, stream>>>(h2s, Wgb, bg, out, NVG);
    gemm_bf16_kernel<<<dim3(4, 196), 256, 0, stream>>>(h2s, Wsb, bs,
                                                       out + (size_t)1024 * NVG, NVS);
  } else {
    gemm_kernel<<<dim3(4, 391), 256, 0, stream>>>(h2s, Wg, bg, out, NVG);
    gemm_kernel<<<dim3(4, 196), 256, 0, stream>>>(h2s, Ws, bs,
                                                  out + (size_t)1024 * NVG, NVS);
  }
  norm_kernel<<<2048, 512, 0, stream>>>(out);
}

// Round 10
// 2851.827 us; speedup vs baseline: 1.1846x; 1.0276x over previous
//
#include <hip/hip_runtime.h>
#include <hip/hip_bf16.h>
#include <stdint.h>

#define T_STEPS 1024
#define NH1 1024
#define NH2 512
#define D_IN 300
#define W1_LD 1324
#define W2_LD 1536
#define NVG 50000
#define NVS 25000
#define NTILE_G 391          // ceil(50000/128)
#define NTILE_S 196          // ceil(25000/128)
#define TPL (NTILE_G + NTILE_S)   // 587 tiles per m-level
#define NTILE (4 * TPL)           // 2348

typedef unsigned long long u64;
typedef __bf16 bf16x8 __attribute__((ext_vector_type(8)));
typedef short s16x8 __attribute__((ext_vector_type(8)));
typedef float f32x4 __attribute__((ext_vector_type(4)));

// ---------------------------------------------------------------------------
// Kernel 1: E[t][r] = b1[r] + sum_c W1[r][c] * X[idx[t]][c]   (c < 300)
// Also zeroes the 64B control block (tail of `out`, overwritten much later).
// ---------------------------------------------------------------------------
__global__ __launch_bounds__(256) void e_kernel(
    const float* __restrict__ X,
    const float* __restrict__ W1,
    const float* __restrict__ b1,
    const int* __restrict__ idx,
    float* __restrict__ E,
    unsigned* __restrict__ ctl)
{
  if (blockIdx.x == 0 && threadIdx.x < 16) ctl[threadIdx.x] = 0u;

  __shared__ float Xs[32 * 300];
  const int rb = blockIdx.x & 7;
  const int tb = blockIdx.x >> 3;
  const int r0 = rb * 128;
  const int t0 = tb * 32;

  for (int t = 0; t < 32; ++t) {
    int node = idx[t0 + t];
    for (int c = threadIdx.x; c < 300; c += 256)
      Xs[t * 300 + c] = X[(size_t)node * D_IN + c];
  }
  __syncthreads();

  const int rl = threadIdx.x & 127;
  const int th = threadIdx.x >> 7;
  const int tbase = th * 16;
  const int r = r0 + rl;

  float acc[16];
  const float bias = b1[r];
#pragma unroll
  for (int tt = 0; tt < 16; ++tt) acc[tt] = bias;

  const float* wrow = W1 + (size_t)r * W1_LD;
  for (int c0 = 0; c0 < 300; c0 += 4) {
    float w0 = wrow[c0 + 0];
    float w1 = wrow[c0 + 1];
    float w2 = wrow[c0 + 2];
    float w3 = wrow[c0 + 3];
#pragma unroll
    for (int tt = 0; tt < 16; ++tt) {
      const float* xr = Xs + (tbase + tt) * 300 + c0;
      acc[tt] += w0 * xr[0] + w1 * xr[1] + w2 * xr[2] + w3 * xr[3];
    }
  }
#pragma unroll
  for (int tt = 0; tt < 16; ++tt)
    E[(size_t)(t0 + tbase + tt) * NH1 + r] = acc[tt];
}

// ---------------------------------------------------------------------------
// Kernel 2: FUSED persistent RNN + GEMM workers.
//
// Election (proven r2-r9): 512 blocks; rank per physical XCD; first XCD to
// fill 32 slots wins. Winners (role 0..31) run the r8-champion RNN (simple
// sc0-sc1 poll — r9's pipelined poll regressed and is reverted). Losers on
// the winning XCD exit (no contention with the latency chain). All other
// blocks become GEMM workers: work-steal 256x128 output tiles (ctl[9]),
// each gated on RNN progress read from buf2 slot-0 tags:
//   tag t0 visible  =>  that wave's iteration-t0 poll (vmcnt(0)) completed
//                   =>  all its stores of iterations < t0 (incl. h2s) drained.
// Gate: need <= tag <= 2048 (range check rejects 0xAA poison). RNN waves
// publish sentinel tag 2048 after a final vmcnt(0) to release level-3 tiles.
// A (h2s) read with sc0 sc1 (probe-coherent vs dirty winning-XCD L2, r3);
// B fp32 + bias plain cached; C plain stores (next-kernel flush, as r3-r9).
// ---------------------------------------------------------------------------
__global__ __launch_bounds__(512, 2) void rnn_kernel(
    const float* __restrict__ W1,
    const float* __restrict__ W2,
    const float* __restrict__ b2,
    const float* __restrict__ E,
    u64* __restrict__ buf1,     // [4][1024]
    u64* __restrict__ buf2,     // [4][512]
    __hip_bfloat16* __restrict__ h2s,   // [T][512]
    unsigned* __restrict__ ctl,         // [8] cnt, [8] winner, [9] tile ctr
    const float* __restrict__ Wg,
    const float* __restrict__ bg,
    const float* __restrict__ Ws,
    const float* __restrict__ bs,
    float* __restrict__ out)
{
  __shared__ float lds1[2][NH1];
  __shared__ float lds2[2][NH2];
  __shared__ short As[256 * 64];
  __shared__ short Bs[128 * 64];
  __shared__ int s_role;
  __shared__ unsigned s_tile;

  // ---- election ----
  if (threadIdx.x == 0) {
    int xcd;
    asm volatile("s_getreg_b32 %0, hwreg(HW_REG_XCC_ID)" : "=s"(xcd));
    xcd &= 7;
    unsigned rk = atomicAdd(&ctl[xcd], 1u);
    unsigned wnr;
    while ((wnr = __hip_atomic_load(&ctl[8], __ATOMIC_RELAXED,
                                    __HIP_MEMORY_SCOPE_AGENT)) == 0u) {
      if (rk == 31u) {
        atomicCAS(&ctl[8], 0u, (unsigned)(xcd + 1));
      } else {
        __builtin_amdgcn_s_sleep(16);
      }
    }
    int role;
    if (wnr == (unsigned)(xcd + 1))
      role = (rk < 32u) ? (int)rk : -2;   // winner : exit (winning XCD)
    else
      role = -1;                          // worker
    s_role = role;
  }
  __syncthreads();
  const int role = s_role;
  if (role == -2) return;

  const int tid = threadIdx.x;
  const int lane = tid & 63;

  if (role >= 0) {
    // ================= RNN path (r8 champion, verbatim) =================
    const int b = role;                           // 0..31
    const int w = tid >> 6;                       // wave 0..7
    const int wvid = b * 8 + w;                   // 0..255
    const int r1 = wvid * 4;
    const int r2 = wvid * 2;
    const int oct = (w + b) & 7;

    float w1r[4][16];
#pragma unroll
    for (int i = 0; i < 4; ++i)
#pragma unroll
      for (int j = 0; j < 16; ++j)
        w1r[i][j] = W1[(size_t)(r1 + i) * W1_LD + D_IN + lane + 64 * j];

    float w2r[2][24];
#pragma unroll
    for (int i = 0; i < 2; ++i)
#pragma unroll
      for (int j = 0; j < 24; ++j)
        w2r[i][j] = W2[(size_t)(r2 + i) * W2_LD + lane + 64 * j];

    const float b2a = b2[r2];
    const float b2b = b2[r2 + 1];

    for (int s = 0; s <= T_STEPS; ++s) {
      float ev = 0.f;
      if (s < T_STEPS) ev = E[(size_t)s * NH1 + r1 + (lane & 3)];

      float v1[2] = {0.f, 0.f};
      float v2 = 0.f;
      unsigned miss = 0;
      if (s >= 1) miss |= 0x3u;
      if (s >= 2) miss |= 0x4u;
      const u64* p1 = buf1 + (size_t)(s & 3) * NH1 + 128 * oct + lane;
      const u64* p2 = buf2 + (size_t)((s - 1) & 3) * NH2 + 64 * oct + lane;
      const unsigned tag1 = (unsigned)s;
      const unsigned tag2 = (unsigned)(s - 1);

      while (miss) {
        u64 t1[2], t2;
        asm volatile(
            "global_load_dwordx2 %0, %3, off sc0 sc1\n\t"
            "global_load_dwordx2 %1, %3, off offset:512 sc0 sc1\n\t"
            "global_load_dwordx2 %2, %4, off sc0 sc1\n\t"
            "s_waitcnt vmcnt(0)"
            : "=&v"(t1[0]), "=&v"(t1[1]), "=&v"(t2)
            : "v"(p1), "v"(p2)
            : "memory");
#pragma unroll
        for (int j = 0; j < 2; ++j)
          if ((miss & (1u << j)) && (unsigned)(t1[j] >> 32) == tag1) {
            v1[j] = __uint_as_float((unsigned)t1[j]);
            miss &= ~(1u << j);
          }
        if ((miss & 0x4u) && (unsigned)(t2 >> 32) == tag2) {
          v2 = __uint_as_float((unsigned)t2);
          miss &= ~0x4u;
        }
      }

      const int pb = s & 1;
#pragma unroll
      for (int j = 0; j < 2; ++j) lds1[pb][128 * oct + 64 * j + lane] = v1[j];
      lds2[pb][64 * oct + lane] = v2;
      __syncthreads();

      float a0 = 0.f, a1 = 0.f, a2 = 0.f, a3 = 0.f, a4 = 0.f, a5 = 0.f;
#pragma unroll
      for (int j = 0; j < 16; ++j) {
        float h = lds1[pb][lane + 64 * j];
        a0 += w1r[0][j] * h;
        a1 += w1r[1][j] * h;
        a2 += w1r[2][j] * h;
        a3 += w1r[3][j] * h;
        a4 += w2r[0][j] * h;
        a5 += w2r[1][j] * h;
      }
#pragma unroll
      for (int j = 0; j < 8; ++j) {
        float h = lds2[pb][lane + 64 * j];
        a4 += w2r[0][16 + j] * h;
        a5 += w2r[1][16 + j] * h;
      }

#pragma unroll
      for (int off = 32; off; off >>= 1) {
        a0 += __shfl_xor(a0, off);
        a1 += __shfl_xor(a1, off);
        a2 += __shfl_xor(a2, off);
        a3 += __shfl_xor(a3, off);
      }
      if (s < T_STEPS && lane < 4) {
        float x = (lane == 0 ? a0 : lane == 1 ? a1 : lane == 2 ? a2 : a3) + ev;
        float h = x > 0.f ? x : 0.01f * x;
        u64 pk = ((u64)(unsigned)(s + 1) << 32) | (u64)__float_as_uint(h);
        u64* dst = buf1 + (size_t)((s + 1) & 3) * NH1 + r1 + lane;
        asm volatile("global_store_dwordx2 %0, %1, off sc0"
                     :: "v"(dst), "v"(pk) : "memory");
      }

      if (s >= 1) {
#pragma unroll
        for (int off = 32; off; off >>= 1) {
          a4 += __shfl_xor(a4, off);
          a5 += __shfl_xor(a5, off);
        }
        if (lane >= 4 && lane < 6) {
          int i = lane - 4;
          float x = (i == 0 ? a4 : a5) + (i == 0 ? b2a : b2b);
          float h = x > 0.f ? x : 0.01f * x;
          u64 pk = ((u64)(unsigned)s << 32) | (u64)__float_as_uint(h);
          u64* dst = buf2 + (size_t)(s & 3) * NH2 + r2 + i;
          asm volatile("global_store_dwordx2 %0, %1, off sc0"
                       :: "v"(dst), "v"(pk) : "memory");
          h2s[(size_t)(s - 1) * NH2 + r2 + i] = __float2bfloat16(h);
        }
      }
    }

    // sentinel: prove ALL h2s stores drained, then release level-3 tiles.
    asm volatile("s_waitcnt vmcnt(0)" ::: "memory");
    if (lane >= 4 && lane < 6) {
      u64 pk = (u64)2048u << 32;
      u64* dst = buf2 + r2 + (lane - 4);   // slot 0
      asm volatile("global_store_dwordx2 %0, %1, off sc0"
                   :: "v"(dst), "v"(pk) : "memory");
    }
    return;
  }

  // ================= worker path: tile-stealing GEMM =================
  {
    const int wv = tid >> 6;
    const int wm = (wv & 1) * 128;
    const int wn = (wv >> 1) * 32;
    const int ml = lane & 15;
    const int kq = lane >> 4;
    const int arow = tid >> 3;           // 0..63
    const int kc = tid & 7;
    const int phys = kc ^ (arow & 7);

    for (;;) {
      if (tid == 0) s_tile = atomicAdd(&ctl[9], 1u);
      __syncthreads();
      const unsigned t = s_tile;
      if (t >= (unsigned)NTILE) break;
      const int lvl = (int)(t / (unsigned)TPL);
      const int rem = (int)(t - (unsigned)lvl * (unsigned)TPL);
      const int seg = rem >= NTILE_G;
      const int nb = seg ? rem - NTILE_G : rem;
      const int m0 = lvl * 256;
      const int n0 = nb * 128;
      const int N = seg ? NVS : NVG;
      const float* B = seg ? Ws : Wg;
      const float* bias = seg ? bs : bg;
      float* C = seg ? out + (size_t)1024 * NVG : out;

      // gate: every RNN wave past the needed step (range check kills poison)
      const unsigned need = (lvl == 3) ? 2048u : (unsigned)(256 * (lvl + 1) + 4);
      {
        const u64* gp = buf2 + tid;      // slot 0, entry tid
        for (;;) {
          u64 v;
          asm volatile("global_load_dwordx2 %0, %1, off sc0 sc1\n\t"
                       "s_waitcnt vmcnt(0)"
                       : "=v"(v) : "v"(gp) : "memory");
          unsigned tg = (unsigned)(v >> 32);
          if (tg >= need && tg <= 2048u) break;
          __builtin_amdgcn_s_sleep(64);
        }
      }
      __syncthreads();

      f32x4 acc[8][2];
#pragma unroll
      for (int i = 0; i < 8; ++i)
#pragma unroll
        for (int j = 0; j < 2; ++j)
          acc[i][j] = (f32x4){0.f, 0.f, 0.f, 0.f};

      for (int kb = 0; kb < 512; kb += 64) {
        __syncthreads();
        // A: 4 x 16B coherent loads (rows arow, arow+64, +128, +192)
        const short* ab = (const short*)h2s + (size_t)(m0 + arow) * 512 + kb + kc * 8;
        s16x8 av0, av1, av2, av3;
        asm volatile(
            "global_load_dwordx4 %0, %4, off sc0 sc1\n\t"
            "global_load_dwordx4 %1, %5, off sc0 sc1\n\t"
            "global_load_dwordx4 %2, %6, off sc0 sc1\n\t"
            "global_load_dwordx4 %3, %7, off sc0 sc1"
            : "=&v"(av0), "=&v"(av1), "=&v"(av2), "=&v"(av3)
            : "v"(ab), "v"(ab + 32768), "v"(ab + 65536), "v"(ab + 98304)
            : "memory");
        // B: 2 rows (arow, arow+64), fp32 -> bf16
        int gr0 = n0 + arow;       if (gr0 >= N) gr0 = N - 1;
        int gr1 = n0 + 64 + arow;  if (gr1 >= N) gr1 = N - 1;
        const float* bp0 = B + (size_t)gr0 * 512 + kb + kc * 8;
        const float* bp1 = B + (size_t)gr1 * 512 + kb + kc * 8;
        f32x4 f00 = ((const f32x4*)bp0)[0], f01 = ((const f32x4*)bp0)[1];
        f32x4 f10 = ((const f32x4*)bp1)[0], f11 = ((const f32x4*)bp1)[1];
        bf16x8 bv0, bv1;
        bv0[0] = (__bf16)f00[0]; bv0[1] = (__bf16)f00[1];
        bv0[2] = (__bf16)f00[2]; bv0[3] = (__bf16)f00[3];
        bv0[4] = (__bf16)f01[0]; bv0[5] = (__bf16)f01[1];
        bv0[6] = (__bf16)f01[2]; bv0[7] = (__bf16)f01[3];
        bv1[0] = (__bf16)f10[0]; bv1[1] = (__bf16)f10[1];
        bv1[2] = (__bf16)f10[2]; bv1[3] = (__bf16)f10[3];
        bv1[4] = (__bf16)f11[0]; bv1[5] = (__bf16)f11[1];
        bv1[6] = (__bf16)f11[2]; bv1[7] = (__bf16)f11[3];
        asm volatile("s_waitcnt vmcnt(0)" ::: "memory");
        *(s16x8*)(As + (arow +   0) * 64 + phys * 8) = av0;
        *(s16x8*)(As + (arow +  64) * 64 + phys * 8) = av1;
        *(s16x8*)(As + (arow + 128) * 64 + phys * 8) = av2;
        *(s16x8*)(As + (arow + 192) * 64 + phys * 8) = av3;
        *(bf16x8*)(Bs + (arow +  0) * 64 + phys * 8) = bv0;
        *(bf16x8*)(Bs + (arow + 64) * 64 + phys * 8) = bv1;
        __syncthreads();
#pragma unroll
        for (int ks = 0; ks < 2; ++ks) {
          bf16x8 af[8], bfr[2];
#pragma unroll
          for (int i = 0; i < 8; ++i) {
            int row = wm + 16 * i + ml;
            int pk2 = (ks * 4 + kq) ^ (row & 7);
            af[i] = *(const bf16x8*)(As + row * 64 + pk2 * 8);
          }
#pragma unroll
          for (int j = 0; j < 2; ++j) {
            int row = wn + 16 * j + ml;
            int pk2 = (ks * 4 + kq) ^ (row & 7);
            bfr[j] = *(const bf16x8*)(Bs + row * 64 + pk2 * 8);
          }
#pragma unroll
          for (int i = 0; i < 8; ++i)
#pragma unroll
            for (int j = 0; j < 2; ++j)
              acc[i][j] = __builtin_amdgcn_mfma_f32_16x16x32_bf16(
                  af[i], bfr[j], acc[i][j], 0, 0, 0);
        }
      }

      float bvv[2];
#pragma unroll
      for (int j = 0; j < 2; ++j) {
        int n = n0 + wn + 16 * j + ml;
        bvv[j] = (n < N) ? bias[n] : 0.f;
      }
#pragma unroll
      for (int i = 0; i < 8; ++i) {
        int mrow = m0 + wm + 16 * i + kq * 4;
#pragma unroll
        for (int j = 0; j < 2; ++j) {
          int n = n0 + wn + 16 * j + ml;
          if (n < N) {
#pragma unroll
            for (int r = 0; r < 4; ++r)
              C[(size_t)(mrow + r) * N + n] = acc[i][j][r] + bvv[j];
          }
        }
      }
    }
  }
}

// ---------------------------------------------------------------------------
// Kernel 4: in-place fp32 log-softmax per (row, segment).
// 2-pass online-LSE, f32x4 vectorized, 512 threads (r9, kept).
// ---------------------------------------------------------------------------
__global__ __launch_bounds__(512) void norm_kernel(float* __restrict__ out)
{
  const int b = blockIdx.x;
  const int t = b & 1023;
  const int seg = b >> 10;
  const size_t base = seg == 0 ? (size_t)t * NVG
                               : (size_t)1024 * NVG + (size_t)t * NVS;
  const int len4 = (seg == 0 ? NVG : NVS) >> 2;
  f32x4* p = (f32x4*)(out + base);
  const int lane = threadIdx.x & 63;
  const int wv = threadIdx.x >> 6;
  __shared__ float redm[8], reds[8];

  float m = -3.0e38f, ssum = 0.f;
  for (int i = threadIdx.x; i < len4; i += 512) {
    f32x4 v = p[i];
    float vm = fmaxf(fmaxf(v[0], v[1]), fmaxf(v[2], v[3]));
    if (vm > m) { ssum *= expf(m - vm); m = vm; }
    ssum += expf(v[0] - m) + expf(v[1] - m) + expf(v[2] - m) + expf(v[3] - m);
  }
#pragma unroll
  for (int off = 32; off; off >>= 1) {
    float mo = __shfl_xor(m, off);
    float so = __shfl_xor(ssum, off);
    float mn = fmaxf(m, mo);
    ssum = ssum * expf(m - mn) + so * expf(mo - mn);
    m = mn;
  }
  if (lane == 0) { redm[wv] = m; reds[wv] = ssum; }
  __syncthreads();
  float M = redm[0], S = reds[0];
#pragma unroll
  for (int k = 1; k < 8; ++k) {
    float mo = redm[k], so = reds[k];
    float mn = fmaxf(M, mo);
    S = S * expf(M - mn) + so * expf(mo - mn);
    M = mn;
  }
  const float lse = M + logf(S);

  for (int i = threadIdx.x; i < len4; i += 512) {
    f32x4 v = p[i];
    v[0] -= lse; v[1] -= lse; v[2] -= lse; v[3] -= lse;
    p[i] = v;
  }
}

// ---------------------------------------------------------------------------
extern "C" void kernel_launch(void* const* d_in, const int* in_sizes, int n_in,
                              void* d_out, int out_size, void* d_ws, size_t ws_size,
                              hipStream_t stream) {
  const float* X  = (const float*)d_in[0];
  const float* W1 = (const float*)d_in[1];
  const float* b1 = (const float*)d_in[2];
  const float* W2 = (const float*)d_in[3];
  const float* b2 = (const float*)d_in[4];
  const float* Wg = (const float*)d_in[5];
  const float* bg = (const float*)d_in[6];
  const float* Ws = (const float*)d_in[7];
  const float* bs = (const float*)d_in[8];
  const int* idx = (const int*)d_in[9];
  float* out = (float*)d_out;

  char* ws = (char*)d_ws;
  float* E = (float*)ws;                                         // 4 MB
  __hip_bfloat16* h2s = (__hip_bfloat16*)(ws + (size_t)4194304); // 1 MB
  u64* buf1 = (u64*)(ws + (size_t)5242880);                      // 32 KB
  u64* buf2 = (u64*)(ws + (size_t)5275648);                      // 16 KB
  // Control block: tail 64B of `out` (written only by the LAST gemm tile).
  unsigned* ctl = (unsigned*)(out + (size_t)1024 * (NVG + NVS) - 16);

  e_kernel<<<256, 256, 0, stream>>>(X, W1, b1, idx, E, ctl);
  rnn_kernel<<<512, 512, 0, stream>>>(W1, W2, b2, E, buf1, buf2, h2s, ctl,
                                      Wg, bg, Ws, bs, out);
  norm_kernel<<<2048, 512, 0, stream>>>(out);
}